// Round 7
// baseline (590.634 us; speedup 1.0000x reference)
//
#include <hip/hip_runtime.h>
#include <cstdint>

#define N_NODES 100000
#define N_EDGES 1600000
#define SCAN_NB 196   // ceil(100000/512)

typedef short bf16x8 __attribute__((ext_vector_type(8)));
typedef float f32x4 __attribute__((ext_vector_type(4)));
typedef float f32x2 __attribute__((ext_vector_type(2)));   // -> v_pk_fma_f32

// ---------- bf16 helpers ----------
__device__ __forceinline__ uint16_t f2bf(float f) {
    uint32_t b = __float_as_uint(f);
    return (uint16_t)((b + 0x7fffu + ((b >> 16) & 1u)) >> 16);  // RNE
}
__device__ __forceinline__ float bfval(uint16_t u) {
    return __uint_as_float(((uint32_t)u) << 16);
}
__device__ __forceinline__ float blo(uint32_t u) { return __uint_as_float(u << 16); }
__device__ __forceinline__ float bhi(uint32_t u) { return __uint_as_float(u & 0xffff0000u); }

__device__ __forceinline__ float fast_rcp(float x) { return __builtin_amdgcn_rcpf(x); }
// butterfly adds via ds_swizzle with literal patterns (no VALU addr setup)
__device__ __forceinline__ float swz_xadd8(float x) {
    int s = __builtin_amdgcn_ds_swizzle(__float_as_int(x), 0x201F);  // lane^8
    return x + __int_as_float(s);
}
__device__ __forceinline__ float swz_xadd16(float x) {
    int s = __builtin_amdgcn_ds_swizzle(__float_as_int(x), 0x401F);  // lane^16
    return x + __int_as_float(s);
}

// ---------- fused weight prep: cvt_w1 | wvec | w2z | mcat ----------
__global__ __launch_bounds__(512) void prep_k(const float* __restrict__ W1,
        const float* __restrict__ W2, const float* __restrict__ attl,
        const float* __restrict__ attr,
        uint16_t* __restrict__ w1hi, uint16_t* __restrict__ w1lo,
        float* __restrict__ wl2, float* __restrict__ wr2,
        uint16_t* __restrict__ w2z, uint16_t* __restrict__ mhi,
        uint16_t* __restrict__ mlo) {
    __shared__ float Wh[64 * 40];
    int b = blockIdx.x, tid = threadIdx.x;
    if (b < 8) {                       // cvt_w1: 4096 work-items
        int gid = b * 512 + tid;
        int c = gid & 63, kg = gid >> 6;
        uint32_t dh[4], dl[4];
        #pragma unroll
        for (int t = 0; t < 4; ++t) {
            float v0 = W1[(kg * 8 + 2 * t) * 64 + c];
            float v1 = W1[(kg * 8 + 2 * t + 1) * 64 + c];
            uint16_t h0 = f2bf(v0), h1 = f2bf(v1);
            uint16_t l0 = f2bf(v0 - bfval(h0)), l1 = f2bf(v1 - bfval(h1));
            dh[t] = h0 | ((uint32_t)h1 << 16);
            dl[t] = l0 | ((uint32_t)l1 << 16);
        }
        *(uint4*)(w1hi + (long)c * 512 + kg * 8) = make_uint4(dh[0], dh[1], dh[2], dh[3]);
        *(uint4*)(w1lo + (long)c * 512 + kg * 8) = make_uint4(dl[0], dl[1], dl[2], dl[3]);
    } else if (b == 8) {               // wvec: 512 items
        int h = tid >> 6, k = tid & 63;
        float sl = 0.f, sr = 0.f;
        #pragma unroll 8
        for (int c = 0; c < 40; ++c) {
            float w = W2[k * 320 + h * 40 + c];
            sl += w * attl[h * 40 + c];
            sr += w * attr[h * 40 + c];
        }
        wl2[tid] = sl; wr2[tid] = sr;
    } else if (b < 57) {               // w2z: 24576 items
        int t = (b - 9) * 512 + tid;
        int c = t >> 9, kap = t & 511;
        int h = kap >> 6, k = kap & 63;
        float v = (c < 40) ? W2[k * 320 + h * 40 + c] : 0.f;
        w2z[c * 512 + kap] = f2bf(v);
    } else {                           // mcat: blocks 57..64, one head each
        int h = b - 57;
        for (int t = tid; t < 2560; t += 512) {
            int k = t / 40, c = t % 40;
            Wh[k * 40 + c] = W2[k * 320 + h * 40 + c];
        }
        __syncthreads();
        #pragma unroll
        for (int r = 0; r < 8; ++r) {
            int o = r * 512 + tid;
            int kp = o >> 6, k = o & 63;
            float s = 0.f;
            #pragma unroll 8
            for (int c = 0; c < 40; ++c) s += Wh[k * 40 + c] * Wh[kp * 40 + c];
            uint16_t hi = f2bf(s);
            uint16_t lo = f2bf(s - bfval(hi));
            mhi[(h * 64 + kp) * 64 + k] = hi;
            mlo[(h * 64 + kp) * 64 + k] = lo;
        }
    }
}

// ---------- GEMM1 (split-bf16 MFMA): xw1 f32 + xw1b bf16 mirror ----------
__global__ __launch_bounds__(512) void gemm1_mfma(const float* __restrict__ x,
        const uint16_t* __restrict__ w1hi, const uint16_t* __restrict__ w1lo,
        float* __restrict__ xw1, uint16_t* __restrict__ xw1b) {
    __shared__ __align__(16) char Ah[128 * 144];
    __shared__ __align__(16) char Al[128 * 144];
    __shared__ __align__(16) char Bh[64 * 144];
    __shared__ __align__(16) char Bl[64 * 144];
    int tid = threadIdx.x;
    int l = tid & 63, w = tid >> 6;
    long base = (long)blockIdx.x * 128;
    f32x4 acc[4];
    #pragma unroll
    for (int ct = 0; ct < 4; ++ct)
        #pragma unroll
        for (int j = 0; j < 4; ++j) acc[ct][j] = 0.f;

    for (int kb = 0; kb < 512; kb += 64) {
        __syncthreads();
        #pragma unroll
        for (int it = 0; it < 2; ++it) {
            int idx = tid + it * 512;
            int row = idx >> 3, kc = idx & 7;
            long r = base + row; if (r >= N_NODES) r = N_NODES - 1;
            const float4* p = (const float4*)(x + r * 512 + kb + kc * 8);
            float4 f0 = p[0], f1 = p[1];
            float v[8] = {f0.x, f0.y, f0.z, f0.w, f1.x, f1.y, f1.z, f1.w};
            uint32_t dh[4], dl[4];
            #pragma unroll
            for (int t = 0; t < 4; ++t) {
                uint16_t h0 = f2bf(v[2 * t]),     h1 = f2bf(v[2 * t + 1]);
                uint16_t l0 = f2bf(v[2 * t] - bfval(h0));
                uint16_t l1 = f2bf(v[2 * t + 1] - bfval(h1));
                dh[t] = h0 | ((uint32_t)h1 << 16);
                dl[t] = l0 | ((uint32_t)l1 << 16);
            }
            *(uint4*)(Ah + row * 144 + kc * 16) = make_uint4(dh[0], dh[1], dh[2], dh[3]);
            *(uint4*)(Al + row * 144 + kc * 16) = make_uint4(dl[0], dl[1], dl[2], dl[3]);
        }
        {
            int c = tid >> 3, kc = tid & 7;
            *(uint4*)(Bh + c * 144 + kc * 16) =
                *(const uint4*)(w1hi + (long)c * 512 + kb + kc * 8);
            *(uint4*)(Bl + c * 144 + kc * 16) =
                *(const uint4*)(w1lo + (long)c * 512 + kb + kc * 8);
        }
        __syncthreads();
        #pragma unroll
        for (int kk = 0; kk < 2; ++kk) {
            int aoff = (w * 16 + (l & 15)) * 144 + kk * 64 + (l >> 4) * 16;
            bf16x8 ah = *(const bf16x8*)(Ah + aoff);
            bf16x8 alo = *(const bf16x8*)(Al + aoff);
            #pragma unroll
            for (int ct = 0; ct < 4; ++ct) {
                int boff = (ct * 16 + (l & 15)) * 144 + kk * 64 + (l >> 4) * 16;
                bf16x8 bh = *(const bf16x8*)(Bh + boff);
                bf16x8 bl = *(const bf16x8*)(Bl + boff);
                acc[ct] = __builtin_amdgcn_mfma_f32_16x16x32_bf16(ah, bh, acc[ct], 0, 0, 0);
                acc[ct] = __builtin_amdgcn_mfma_f32_16x16x32_bf16(alo, bh, acc[ct], 0, 0, 0);
                acc[ct] = __builtin_amdgcn_mfma_f32_16x16x32_bf16(ah, bl, acc[ct], 0, 0, 0);
            }
        }
    }
    int nrow = w * 16 + (l >> 4) * 4;
    #pragma unroll
    for (int ct = 0; ct < 4; ++ct)
        #pragma unroll
        for (int j = 0; j < 4; ++j) {
            long node = base + nrow + j;
            if (node < N_NODES) {
                int col = ct * 16 + (l & 15);
                xw1[node * 64 + col] = acc[ct][j];
                xw1b[node * 64 + col] = f2bf(acc[ct][j]);
            }
        }
}

// ---------- YGEMM: Y[i][kappa'] = h_bf16 @ Mcat(split), plain [i][kappa] bf16 ----------
__global__ __launch_bounds__(512) void ygemm_mfma(const uint16_t* __restrict__ hjb,
        const uint16_t* __restrict__ mhi, const uint16_t* __restrict__ mlo,
        uint16_t* __restrict__ Y16) {
    __shared__ __align__(16) char Bh[256 * 144];
    __shared__ __align__(16) char Bl[256 * 144];
    int tid = threadIdx.x;
    int l = tid & 63, w = tid >> 6;
    int half = blockIdx.x & 1;
    long base = (long)(blockIdx.x >> 1) * 128;
    #pragma unroll
    for (int it = 0; it < 4; ++it) {
        int idx = tid + it * 512;
        int c = idx >> 3, kc = idx & 7;
        *(uint4*)(Bh + c * 144 + kc * 16) =
            *(const uint4*)(mhi + (long)(half * 256 + c) * 64 + kc * 8);
        *(uint4*)(Bl + c * 144 + kc * 16) =
            *(const uint4*)(mlo + (long)(half * 256 + c) * 64 + kc * 8);
    }
    long n0 = base + w * 16 + (l & 15);
    long nld = n0 < N_NODES ? n0 : N_NODES - 1;
    bf16x8 a[2];
    #pragma unroll
    for (int kk = 0; kk < 2; ++kk)
        a[kk] = *(const bf16x8*)(hjb + nld * 64 + kk * 32 + (l >> 4) * 8);
    __syncthreads();
    f32x4 acc[16];
    #pragma unroll
    for (int ct = 0; ct < 16; ++ct)
        #pragma unroll
        for (int j = 0; j < 4; ++j) acc[ct][j] = 0.f;
    #pragma unroll
    for (int ct = 0; ct < 16; ++ct) {
        #pragma unroll
        for (int kk = 0; kk < 2; ++kk) {
            bf16x8 bh = *(const bf16x8*)(Bh + (ct * 16 + (l & 15)) * 144 + kk * 64 + (l >> 4) * 16);
            bf16x8 bl = *(const bf16x8*)(Bl + (ct * 16 + (l & 15)) * 144 + kk * 64 + (l >> 4) * 16);
            acc[ct] = __builtin_amdgcn_mfma_f32_16x16x32_bf16(bh, a[kk], acc[ct], 0, 0, 0);
            acc[ct] = __builtin_amdgcn_mfma_f32_16x16x32_bf16(bl, a[kk], acc[ct], 0, 0, 0);
        }
    }
    if (n0 < N_NODES) {
        uint32_t* Yd = (uint32_t*)Y16;
        #pragma unroll
        for (int ct = 0; ct < 16; ++ct) {
            int kp = half * 256 + ct * 16 + (l >> 4) * 4;   // kappa' of acc[ct][0]
            uint32_t d0 = f2bf(acc[ct][0]) | ((uint32_t)f2bf(acc[ct][1]) << 16);
            uint32_t d1 = f2bf(acc[ct][2]) | ((uint32_t)f2bf(acc[ct][3]) << 16);
            Yd[n0 * 256 + (kp >> 1)]     = d0;
            Yd[n0 * 256 + (kp >> 1) + 1] = d1;
        }
    }
}

// ---------- CSR build (csr stores src*8) ----------
__global__ void hist_k(const int* __restrict__ dst, int* __restrict__ deg) {
    int e = blockIdx.x * blockDim.x + threadIdx.x;
    if (e < N_EDGES) atomicAdd(&deg[dst[e]], 1);
}

__global__ __launch_bounds__(512) void scan_a(const int* __restrict__ deg,
        int* __restrict__ offs, int* __restrict__ btot) {
    __shared__ int sh[512];
    int t = threadIdx.x;
    int g = blockIdx.x * 512 + t;
    int v = (g < N_NODES) ? deg[g] : 0;
    sh[t] = v;
    __syncthreads();
    #pragma unroll
    for (int o = 1; o < 512; o <<= 1) {
        int add = (t >= o) ? sh[t - o] : 0;
        __syncthreads();
        sh[t] += add;
        __syncthreads();
    }
    if (g < N_NODES) offs[g] = sh[t] - v;
    if (t == 511) btot[blockIdx.x] = sh[511];
}

__global__ __launch_bounds__(256) void scan_b(int* __restrict__ btot) {
    __shared__ int sh[256];
    int t = threadIdx.x;
    int v = (t < SCAN_NB) ? btot[t] : 0;
    sh[t] = v;
    __syncthreads();
    #pragma unroll
    for (int o = 1; o < 256; o <<= 1) {
        int add = (t >= o) ? sh[t - o] : 0;
        __syncthreads();
        sh[t] += add;
        __syncthreads();
    }
    if (t < SCAN_NB) btot[t] = sh[t] - v;
}

__global__ __launch_bounds__(512) void scan_c(int* __restrict__ offs,
        const int* __restrict__ btot, int* __restrict__ cursor) {
    int g = blockIdx.x * 512 + threadIdx.x;
    if (g < N_NODES) {
        int o = offs[g] + btot[blockIdx.x];
        offs[g] = o;
        cursor[g] = o;
    }
}

__global__ void scatter_k(const int* __restrict__ src, const int* __restrict__ dst,
        int* __restrict__ cursor, int* __restrict__ csr8) {
    int e = blockIdx.x * blockDim.x + threadIdx.x;
    if (e < N_EDGES) {
        int pos = atomicAdd(&cursor[dst[e]], 1);
        csr8[pos] = src[e] << 3;
    }
}

// ---------- conv1: head-per-lane; bf16 gathers; 3-deep pipeline; fused al/ar ----------
__global__ __launch_bounds__(256) void conv1_node(const float* __restrict__ xw,
        const uint16_t* __restrict__ xwb,
        const int* __restrict__ offs, const int* __restrict__ deg,
        const int* __restrict__ csr8, const float* __restrict__ att_l,
        const float* __restrict__ att_r, const float* __restrict__ b1,
        const float* __restrict__ wl2, const float* __restrict__ wr2,
        uint16_t* __restrict__ hjb, float* __restrict__ al, float* __restrict__ ar) {
    int wid = (blockIdx.x * blockDim.x + threadIdx.x) >> 6;
    if (wid >= N_NODES) return;
    int i = wid;
    int lane = threadIdx.x & 63;
    int g = lane >> 3, h = lane & 7;
    const float4* rowi = (const float4*)(xw + (long)i * 64 + h * 8);
    float4 xi0 = rowi[0], xi1 = rowi[1];
    f32x2 xip[4] = {{xi0.x, xi0.y}, {xi0.z, xi0.w}, {xi1.x, xi1.y}, {xi1.z, xi1.w}};
    const float4* alp4 = (const float4*)(att_l + h * 8);
    float4 t0 = alp4[0], t1 = alp4[1];
    f32x2 atlp[4] = {{t0.x, t0.y}, {t0.z, t0.w}, {t1.x, t1.y}, {t1.z, t1.w}};
    const float4* arp4 = (const float4*)(att_r + h * 8);
    float4 u0 = arp4[0], u1 = arp4[1];
    f32x2 atrp[4] = {{u0.x, u0.y}, {u0.z, u0.w}, {u1.x, u1.y}, {u1.z, u1.w}};
    f32x2 prp = xip[0] * atrp[0];
    prp += xip[1] * atrp[1];
    prp += xip[2] * atrp[2];
    prp += xip[3] * atrp[3];
    float pr = prp.x + prp.y;
    f32x2 accp[4] = {{0.f,0.f},{0.f,0.f},{0.f,0.f},{0.f,0.f}};
    float den = 0.f;
    int off = offs[i], dg = deg[i];

    auto CORE1 = [&](const f32x2* xjp, bool valid) {
        f32x2 qdp = xip[0] * xjp[0];
        qdp += xip[1] * xjp[1];
        qdp += xip[2] * xjp[2];
        qdp += xip[3] * xjp[3];
        f32x2 qlp = xjp[0] * atlp[0];
        qlp += xjp[1] * atlp[1];
        qlp += xjp[2] * atlp[2];
        qlp += xjp[3] * atlp[3];
        float qd = qdp.x + qdp.y, ql = qlp.x + qlp.y;
        float a = (ql + pr) * fast_rcp(1.0f + __expf(-qd));
        a = fmaxf(a, 0.2f * a);
        float e = __expf(a);
        e = valid ? e : 0.f;
        den += e;
        f32x2 ev = {e, e};
        accp[0] += ev * xjp[0];
        accp[1] += ev * xjp[1];
        accp[2] += ev * xjp[2];
        accp[3] += ev * xjp[3];
    };
    auto C1Q = [&](uint4 q, bool valid) {
        f32x2 ap[4] = {{blo(q.x), bhi(q.x)}, {blo(q.y), bhi(q.y)},
                       {blo(q.z), bhi(q.z)}, {blo(q.w), bhi(q.w)}};
        CORE1(ap, valid);
    };
    auto LI = [&](int S) -> int {
        int p = off + g + 8 * S;
        p = p < N_EDGES ? p : N_EDGES - 1;
        return csr8[p];                 // src*8
    };
    auto RW = [&](uint4& q, int j) {
        q = *(const uint4*)(xwb + (long)j * 8 + h * 8);
    };

    CORE1(xip, g == 0);                 // self loop

    int nS = (dg + 7) >> 3;
    int jA = LI(0), jB = LI(1), jC = LI(2);
    uint4 qA, qB, qC;
    RW(qA, jA); jA = LI(3);
    RW(qB, jB); jB = LI(4);
    RW(qC, jC); jC = LI(5);
    int S = 0;
    while (S + 3 <= nS) {
        C1Q(qA, g + 8 * S < dg);       RW(qA, jA); jA = LI(S + 6);
        C1Q(qB, g + 8 * (S + 1) < dg); RW(qB, jB); jB = LI(S + 7);
        C1Q(qC, g + 8 * (S + 2) < dg); RW(qC, jC); jC = LI(S + 8);
        S += 3;
    }
    if (S < nS)     C1Q(qA, g + 8 * S < dg);
    if (S + 1 < nS) C1Q(qB, g + 8 * (S + 1) < dg);

    float acc[8] = {accp[0].x, accp[0].y, accp[1].x, accp[1].y,
                    accp[2].x, accp[2].y, accp[3].x, accp[3].y};
    #pragma unroll
    for (int o = 8; o <= 32; o <<= 1) {
        #pragma unroll
        for (int t = 0; t < 8; ++t) acc[t] += __shfl_xor(acc[t], o);
        den += __shfl_xor(den, o);
    }
    // all lanes hold full sums for head h -> ELU'd h-row slice
    float inv = fast_rcp(den + 1e-16f);
    const float4* bp4 = (const float4*)(b1 + h * 8);
    float4 c0 = bp4[0], c1 = bp4[1];
    float bias[8] = {c0.x, c0.y, c0.z, c0.w, c1.x, c1.y, c1.z, c1.w};
    float ov[8];
    #pragma unroll
    for (int t = 0; t < 8; ++t) {
        float v = acc[t] * inv + bias[t];
        ov[t] = v > 0.f ? v : __expf(v) - 1.0f;
    }
    if (g == 0) {
        uint32_t d0 = f2bf(ov[0]) | ((uint32_t)f2bf(ov[1]) << 16);
        uint32_t d1 = f2bf(ov[2]) | ((uint32_t)f2bf(ov[3]) << 16);
        uint32_t d2 = f2bf(ov[4]) | ((uint32_t)f2bf(ov[5]) << 16);
        uint32_t d3 = f2bf(ov[6]) | ((uint32_t)f2bf(ov[7]) << 16);
        *(uint4*)(hjb + (long)i * 64 + h * 8) = make_uint4(d0, d1, d2, d3);
    }
    // fused al/ar: lane (g,h) dots its 8 h-vals with wl2[g][h*8..], reduce over h
    {
        const float4* wlp = (const float4*)(wl2 + g * 64 + h * 8);
        float4 w0 = wlp[0], w1 = wlp[1];
        const float4* wrp = (const float4*)(wr2 + g * 64 + h * 8);
        float4 r0 = wrp[0], r1 = wrp[1];
        float sl = ov[0]*w0.x + ov[1]*w0.y + ov[2]*w0.z + ov[3]*w0.w
                 + ov[4]*w1.x + ov[5]*w1.y + ov[6]*w1.z + ov[7]*w1.w;
        float sr = ov[0]*r0.x + ov[1]*r0.y + ov[2]*r0.z + ov[3]*r0.w
                 + ov[4]*r1.x + ov[5]*r1.y + ov[6]*r1.z + ov[7]*r1.w;
        #pragma unroll
        for (int o = 1; o <= 4; o <<= 1) {
            sl += __shfl_xor(sl, o);
            sr += __shfl_xor(sr, o);
        }
        if (h == 0) {
            al[i * 8 + g] = sl;
            ar[i * 8 + g] = sr;
        }
    }
}

// ---------- conv2 (h-space): wave-per-node; ungated pair loop; 3-deep copy-free
//            pipeline; ds_swizzle reduce; z = agg/(8*den) bf16 in place over Y ----------
__global__ __launch_bounds__(256) void conv2_node(const uint16_t* __restrict__ hjb16,
        const int* __restrict__ offs, const int* __restrict__ deg,
        const int* __restrict__ csr8, const float* __restrict__ al,
        const float* __restrict__ ar, uint32_t* __restrict__ Yd) {
    int wid = (blockIdx.x * 256 + threadIdx.x) >> 6;
    if (wid >= N_NODES) return;
    int i = wid;
    int lane = threadIdx.x & 63;
    int half = lane >> 5;
    int lam = lane & 7, r2 = (lane >> 3) & 3;
    const uint4* hj4 = (const uint4*)hjb16;        // 8 uint4 per row
    int r22 = r2 * 2;
    unsigned ydw = (unsigned)i * 256u + (unsigned)lam * 32u + (unsigned)r2 * 8u;

    // y_i slice: head lam, dims 16*r2..16*r2+15
    f32x2 y[8];
    {
        uint4 a = *(const uint4*)(Yd + ydw);
        uint4 b = *(const uint4*)(Yd + ydw + 4);
        uint32_t d[8] = {a.x, a.y, a.z, a.w, b.x, b.y, b.z, b.w};
        #pragma unroll
        for (int t = 0; t < 8; ++t) y[t] = (f32x2){blo(d[t]), bhi(d[t])};
    }
    float ari = ar[i * 8 + lam];
    f32x2 agg[8];
    #pragma unroll
    for (int t = 0; t < 8; ++t) agg[t] = (f32x2){0.f, 0.f};
    float den = 0.f;
    int off = offs[i], dg = deg[i];

    auto CORE = [&](const uint32_t* D, float alv) {
        f32x2 h[8];
        #pragma unroll
        for (int t = 0; t < 8; ++t) h[t] = (f32x2){blo(D[t]), bhi(D[t])};
        f32x2 pp = y[0] * h[0];
        #pragma unroll
        for (int t = 1; t < 8; ++t) pp += y[t] * h[t];
        float pd = pp.x + pp.y;
        pd = swz_xadd8(pd);
        pd = swz_xadd16(pd);
        float a = (alv + ari) * fast_rcp(1.0f + __expf(-pd));
        a = fmaxf(a, 0.2f * a);
        float e = __expf(a);
        den += e;
        f32x2 ev = {e, e};
        #pragma unroll
        for (int t = 0; t < 8; ++t) agg[t] += ev * h[t];
    };
    auto COREG = [&](const uint32_t* D, float alv, bool valid) {
        f32x2 h[8];
        #pragma unroll
        for (int t = 0; t < 8; ++t) h[t] = (f32x2){blo(D[t]), bhi(D[t])};
        f32x2 pp = y[0] * h[0];
        #pragma unroll
        for (int t = 1; t < 8; ++t) pp += y[t] * h[t];
        float pd = pp.x + pp.y;
        pd = swz_xadd8(pd);
        pd = swz_xadd16(pd);
        float a = (alv + ari) * fast_rcp(1.0f + __expf(-pd));
        a = fmaxf(a, 0.2f * a);
        float e = __expf(a);
        e = valid ? e : 0.f;
        den += e;
        f32x2 ev = {e, e};
        #pragma unroll
        for (int t = 0; t < 8; ++t) agg[t] += ev * h[t];
    };
    auto LIDX = [&](int p) -> int {
        p = p < N_EDGES ? p : N_EDGES - 1;         // position clamp only
        return csr8[p];                            // src*8
    };
    auto ROW = [&](uint32_t* D, float& A, int j) {
        const uint4* r = hj4 + (unsigned)j + r22;
        uint4 a = r[0], b = r[1];
        D[0] = a.x; D[1] = a.y; D[2] = a.z; D[3] = a.w;
        D[4] = b.x; D[5] = b.y; D[6] = b.z; D[7] = b.w;
        A = al[j + lam];
    };

    // self loop (half 0 only contributes)
    {
        uint32_t DS[8]; float AS;
        ROW(DS, AS, i * 8);
        COREG(DS, AS, half == 0);
    }

    int nP = dg >> 1;                 // full pairs: positions 2s+half all valid
    int base = off + half;
    uint32_t RA[8], RB[8], RC[8];
    float AA, AB, AC;
    int jA = LIDX(base), jB = LIDX(base + 2), jC = LIDX(base + 4);
    ROW(RA, AA, jA); jA = LIDX(base + 6);
    ROW(RB, AB, jB); jB = LIDX(base + 8);
    ROW(RC, AC, jC); jC = LIDX(base + 10);
    int s = 0;
    while (s + 3 <= nP) {             // 3-deep, copy-free
        CORE(RA, AA); ROW(RA, AA, jA); jA = LIDX(base + 2 * s + 12);
        CORE(RB, AB); ROW(RB, AB, jB); jB = LIDX(base + 2 * s + 14);
        CORE(RC, AC); ROW(RC, AC, jC); jC = LIDX(base + 2 * s + 16);
        s += 3;
    }
    int rem = nP - s;                 // 0..2; RA=pair s, RB=pair s+1
    if (rem >= 1) CORE(RA, AA);
    if (rem >= 2) CORE(RB, AB);
    if (dg & 1) {                     // odd tail: position dg-1, half 0 only
        uint32_t RT[8]; float AT;
        ROW(RT, AT, LIDX(off + dg - 1));
        COREG(RT, AT, half == 0);
    }

    // merge halves
    den += __shfl_xor(den, 32);
    #pragma unroll
    for (int t = 0; t < 8; ++t) {
        agg[t].x += __shfl_xor(agg[t].x, 32);
        agg[t].y += __shfl_xor(agg[t].y, 32);
    }
    float inv = 0.125f * fast_rcp(den + 1e-16f);
    if (half == 0) {
        uint32_t zd[8];
        #pragma unroll
        for (int t = 0; t < 8; ++t) {
            float zx = agg[t].x * inv, zy = agg[t].y * inv;
            zd[t] = f2bf(zx) | ((uint32_t)f2bf(zy) << 16);
        }
        *(uint4*)(Yd + ydw)     = make_uint4(zd[0], zd[1], zd[2], zd[3]);
        *(uint4*)(Yd + ydw + 4) = make_uint4(zd[4], zd[5], zd[6], zd[7]);
    }
}

// ---------- ZGEMM: out = Z @ B + b2, fused row log_softmax ----------
__global__ __launch_bounds__(512) void zgemm_mfma(const uint32_t* __restrict__ Zd,
        const uint16_t* __restrict__ w2z, const float* __restrict__ b2,
        float* __restrict__ out) {
    __shared__ __align__(16) uint16_t Bsm[48 * 520];
    int tid = threadIdx.x;
    int l = tid & 63, w = tid >> 6;
    long base = (long)blockIdx.x * 128;
    for (int q = tid; q < 3072; q += 512) {
        int c = q >> 6, k8 = (q & 63) * 8;
        *(uint4*)(Bsm + c * 520 + k8) = *(const uint4*)(w2z + c * 512 + k8);
    }
    if (blockIdx.x == 0 && tid == 0) out[(long)N_NODES * 40] = 0.0f;  // att_loss
    __syncthreads();
    long n0 = base + w * 16 + (l & 15);
    long nld = n0 < N_NODES ? n0 : N_NODES - 1;
    f32x4 acc[3];
    #pragma unroll
    for (int ct = 0; ct < 3; ++ct)
        #pragma unroll
        for (int j = 0; j < 4; ++j) acc[ct][j] = 0.f;
    #pragma unroll
    for (int kb = 0; kb < 16; ++kb) {
        bf16x8 a = *(const bf16x8*)(Zd + nld * 256 + kb * 16 + (l >> 4) * 4);
        #pragma unroll
        for (int ct = 0; ct < 3; ++ct) {
            bf16x8 b = *(const bf16x8*)(Bsm + (ct * 16 + (l & 15)) * 520 + kb * 32 + (l >> 4) * 8);
            acc[ct] = __builtin_amdgcn_mfma_f32_16x16x32_bf16(b, a, acc[ct], 0, 0, 0);
        }
    }
    float v[12];
    int cb0 = (l >> 4) * 4;
    #pragma unroll
    for (int ct = 0; ct < 3; ++ct)
        #pragma unroll
        for (int j = 0; j < 4; ++j) {
            int cb = ct * 16 + cb0 + j;
            v[ct * 4 + j] = (cb < 40) ? acc[ct][j] + b2[cb] : -1e30f;
        }
    float mx = v[0];
    #pragma unroll
    for (int t = 1; t < 12; ++t) mx = fmaxf(mx, v[t]);
    mx = fmaxf(mx, __shfl_xor(mx, 16));
    mx = fmaxf(mx, __shfl_xor(mx, 32));
    float sm = 0.f;
    #pragma unroll
    for (int t = 0; t < 12; ++t) sm += (v[t] > -1e29f) ? __expf(v[t] - mx) : 0.f;
    sm += __shfl_xor(sm, 16);
    sm += __shfl_xor(sm, 32);
    float lse = mx + __logf(sm);
    if (n0 < N_NODES) {
        #pragma unroll
        for (int ct = 0; ct < 3; ++ct)
            #pragma unroll
            for (int j = 0; j < 4; ++j) {
                int cb = ct * 16 + cb0 + j;
                if (cb < 40) out[n0 * 40 + cb] = v[ct * 4 + j] - lse;
            }
    }
}

extern "C" void kernel_launch(void* const* d_in, const int* in_sizes, int n_in,
                              void* d_out, int out_size, void* d_ws, size_t ws_size,
                              hipStream_t stream) {
    const float* x      = (const float*)d_in[0];
    const int*   ei     = (const int*)d_in[1];
    const float* W1     = (const float*)d_in[2];
    const float* att_l1 = (const float*)d_in[3];
    const float* att_r1 = (const float*)d_in[4];
    const float* b1     = (const float*)d_in[5];
    const float* W2     = (const float*)d_in[6];
    const float* att_l2 = (const float*)d_in[7];
    const float* att_r2 = (const float*)d_in[8];
    const float* b2     = (const float*)d_in[9];
    const int* src = ei;
    const int* dst = ei + N_EDGES;
    float* out = (float*)d_out;

    char* ws = (char*)d_ws;
    // Y (102.4 MB) aliases xw1 (25.6) + xw1b (12.8): both dead before ygemm.
    uint16_t* Y      = (uint16_t*)(ws + 0);          // 102.4 MB (later: Z)
    float*    xw1    = (float*)(ws + 0);             // 25.6 MB (dead after conv1)
    uint16_t* xw1b   = (uint16_t*)(ws + 25600000);   // 12.8 MB (dead after conv1)
    uint16_t* hjb    = (uint16_t*)(ws + 102400000);  // 12.8 MB (bf16 h rows)
    float*    al     = (float*)(ws + 115200000);     // 3.2 MB
    float*    ar     = (float*)(ws + 118400000);     // 3.2 MB
    int*      deg    = (int*)(ws + 121600000);       // 400 KB
    int*      offs   = (int*)(ws + 122000000);       // 400 KB
    int*      cursor = (int*)(ws + 122400000);       // 400 KB
    int*      btot   = (int*)(ws + 122800000);       // 1 KB
    int*      csr8   = (int*)(ws + 122801024);       // 6.4 MB
    uint16_t* w1hi   = (uint16_t*)(ws + 129201024);  // 64 KB
    uint16_t* w1lo   = (uint16_t*)(ws + 129266560);  // 64 KB
    uint16_t* mhi    = (uint16_t*)(ws + 129332096);  // 64 KB
    uint16_t* mlo    = (uint16_t*)(ws + 129397632);  // 64 KB
    uint16_t* w2z    = (uint16_t*)(ws + 129463168);  // 48 KB
    float*    wl2    = (float*)(ws + 129512320);     // 2 KB
    float*    wr2    = (float*)(ws + 129514368);     // 2 KB -> ~129.5 MB total

    hipMemsetAsync(deg, 0, (size_t)N_NODES * 4, stream);

    // fused weight prep (blocks: 0-7 cvt_w1 | 8 wvec | 9-56 w2z | 57-64 mcat)
    prep_k<<<65, 512, 0, stream>>>(W1, W2, att_l2, att_r2,
                                   w1hi, w1lo, wl2, wr2, w2z, mhi, mlo);

    // CSR build (dst-sorted adjacency; csr stores src*8)
    hist_k<<<6250, 256, 0, stream>>>(dst, deg);
    scan_a<<<SCAN_NB, 512, 0, stream>>>(deg, offs, btot);
    scan_b<<<1, 256, 0, stream>>>(btot);
    scan_c<<<SCAN_NB, 512, 0, stream>>>(offs, btot, cursor);
    scatter_k<<<6250, 256, 0, stream>>>(src, dst, cursor, csr8);

    // conv1 (al/ar fused into epilogue)
    gemm1_mfma<<<782, 512, 0, stream>>>(x, w1hi, w1lo, xw1, xw1b);
    conv1_node<<<25000, 256, 0, stream>>>(xw1, xw1b, offs, deg, csr8,
                                          att_l1, att_r1, b1, wl2, wr2,
                                          hjb, al, ar);

    // Y = h @ Mcat (after conv1: Y aliases xw1/xw1b)
    ygemm_mfma<<<1564, 512, 0, stream>>>(hjb, mhi, mlo, Y);

    // conv2: h-space attention; writes Z in place over Y
    conv2_node<<<25000, 256, 0, stream>>>(hjb, offs, deg, csr8, al, ar, (uint32_t*)Y);

    // out = Z @ B + b2, fused log_softmax
    zgemm_mfma<<<782, 512, 0, stream>>>((const uint32_t*)Y, w2z, b2, out);
}

// Round 8
// 526.864 us; speedup vs baseline: 1.1210x; 1.1210x over previous
//
#include <hip/hip_runtime.h>
#include <cstdint>

#define N_NODES 100000
#define N_EDGES 1600000
#define SCAN_NB 196   // ceil(100000/512)

typedef short bf16x8 __attribute__((ext_vector_type(8)));
typedef float f32x4 __attribute__((ext_vector_type(4)));
typedef float f32x2 __attribute__((ext_vector_type(2)));   // -> v_pk_fma_f32

// ---------- bf16 helpers ----------
__device__ __forceinline__ uint16_t f2bf(float f) {
    uint32_t b = __float_as_uint(f);
    return (uint16_t)((b + 0x7fffu + ((b >> 16) & 1u)) >> 16);  // RNE
}
__device__ __forceinline__ float bfval(uint16_t u) {
    return __uint_as_float(((uint32_t)u) << 16);
}
__device__ __forceinline__ float blo(uint32_t u) { return __uint_as_float(u << 16); }
__device__ __forceinline__ float bhi(uint32_t u) { return __uint_as_float(u & 0xffff0000u); }

// ---------- fast math helpers ----------
__device__ __forceinline__ float fast_rcp(float x) { return __builtin_amdgcn_rcpf(x); }
// in-quad butterfly adds via DPP quad_perm
__device__ __forceinline__ float dpp_xadd1(float x) {
    int s = __builtin_amdgcn_update_dpp(0, __float_as_int(x), 0xB1, 0xF, 0xF, true); // [1,0,3,2]
    return x + __int_as_float(s);
}
__device__ __forceinline__ float dpp_xadd2(float x) {
    int s = __builtin_amdgcn_update_dpp(0, __float_as_int(x), 0x4E, 0xF, 0xF, true); // [2,3,0,1]
    return x + __int_as_float(s);
}

// ---------- fused weight prep: cvt_w1 (blocks 0-7) | wvec (8) | cvt_w2 (9) ----------
__global__ __launch_bounds__(512) void prep_k(const float* __restrict__ W1,
        const float* __restrict__ W2, const float* __restrict__ attl,
        const float* __restrict__ attr,
        uint16_t* __restrict__ w1hi, uint16_t* __restrict__ w1lo,
        float* __restrict__ wl2, float* __restrict__ wr2,
        uint16_t* __restrict__ w2T) {
    int b = blockIdx.x, tid = threadIdx.x;
    if (b < 8) {                       // cvt_w1: 4096 work-items (split bf16 hi/lo)
        int gid = b * 512 + tid;
        int c = gid & 63, kg = gid >> 6;
        uint32_t dh[4], dl[4];
        #pragma unroll
        for (int t = 0; t < 4; ++t) {
            float v0 = W1[(kg * 8 + 2 * t) * 64 + c];
            float v1 = W1[(kg * 8 + 2 * t + 1) * 64 + c];
            uint16_t h0 = f2bf(v0), h1 = f2bf(v1);
            uint16_t l0 = f2bf(v0 - bfval(h0)), l1 = f2bf(v1 - bfval(h1));
            dh[t] = h0 | ((uint32_t)h1 << 16);
            dl[t] = l0 | ((uint32_t)l1 << 16);
        }
        *(uint4*)(w1hi + (long)c * 512 + kg * 8) = make_uint4(dh[0], dh[1], dh[2], dh[3]);
        *(uint4*)(w1lo + (long)c * 512 + kg * 8) = make_uint4(dl[0], dl[1], dl[2], dl[3]);
    } else if (b == 8) {               // wvec: wl2[h][64] = W2_h @ att_l2_h
        int h = tid >> 6, k = tid & 63;
        float sl = 0.f, sr = 0.f;
        #pragma unroll 8
        for (int c = 0; c < 40; ++c) {
            float w = W2[k * 320 + h * 40 + c];
            sl += w * attl[h * 40 + c];
            sr += w * attr[h * 40 + c];
        }
        wl2[tid] = sl; wr2[tid] = sr;
    } else {                           // cvt_w2: col-major [col:320][k:64] bf16
        int c = tid;
        if (c < 320) {
            for (int kg = 0; kg < 8; ++kg) {
                uint32_t d[4];
                #pragma unroll
                for (int t = 0; t < 4; ++t) {
                    float v0 = W2[(kg * 8 + 2 * t) * 320 + c];
                    float v1 = W2[(kg * 8 + 2 * t + 1) * 320 + c];
                    d[t] = f2bf(v0) | ((uint32_t)f2bf(v1) << 16);
                }
                *(uint4*)(w2T + (long)c * 64 + kg * 8) = make_uint4(d[0], d[1], d[2], d[3]);
            }
        }
    }
}

// ---------- GEMM1 (split-bf16 MFMA): xw1 f32 + xw1b bf16 mirror ----------
__global__ __launch_bounds__(512) void gemm1_mfma(const float* __restrict__ x,
        const uint16_t* __restrict__ w1hi, const uint16_t* __restrict__ w1lo,
        float* __restrict__ xw1, uint16_t* __restrict__ xw1b) {
    __shared__ __align__(16) char Ah[128 * 144];
    __shared__ __align__(16) char Al[128 * 144];
    __shared__ __align__(16) char Bh[64 * 144];
    __shared__ __align__(16) char Bl[64 * 144];
    int tid = threadIdx.x;
    int l = tid & 63, w = tid >> 6;
    long base = (long)blockIdx.x * 128;
    f32x4 acc[4];
    #pragma unroll
    for (int ct = 0; ct < 4; ++ct)
        #pragma unroll
        for (int j = 0; j < 4; ++j) acc[ct][j] = 0.f;

    for (int kb = 0; kb < 512; kb += 64) {
        __syncthreads();
        #pragma unroll
        for (int it = 0; it < 2; ++it) {
            int idx = tid + it * 512;
            int row = idx >> 3, kc = idx & 7;
            long r = base + row; if (r >= N_NODES) r = N_NODES - 1;
            const float4* p = (const float4*)(x + r * 512 + kb + kc * 8);
            float4 f0 = p[0], f1 = p[1];
            float v[8] = {f0.x, f0.y, f0.z, f0.w, f1.x, f1.y, f1.z, f1.w};
            uint32_t dh[4], dl[4];
            #pragma unroll
            for (int t = 0; t < 4; ++t) {
                uint16_t h0 = f2bf(v[2 * t]),     h1 = f2bf(v[2 * t + 1]);
                uint16_t l0 = f2bf(v[2 * t] - bfval(h0));
                uint16_t l1 = f2bf(v[2 * t + 1] - bfval(h1));
                dh[t] = h0 | ((uint32_t)h1 << 16);
                dl[t] = l0 | ((uint32_t)l1 << 16);
            }
            *(uint4*)(Ah + row * 144 + kc * 16) = make_uint4(dh[0], dh[1], dh[2], dh[3]);
            *(uint4*)(Al + row * 144 + kc * 16) = make_uint4(dl[0], dl[1], dl[2], dl[3]);
        }
        {
            int c = tid >> 3, kc = tid & 7;
            *(uint4*)(Bh + c * 144 + kc * 16) =
                *(const uint4*)(w1hi + (long)c * 512 + kb + kc * 8);
            *(uint4*)(Bl + c * 144 + kc * 16) =
                *(const uint4*)(w1lo + (long)c * 512 + kb + kc * 8);
        }
        __syncthreads();
        #pragma unroll
        for (int kk = 0; kk < 2; ++kk) {
            int aoff = (w * 16 + (l & 15)) * 144 + kk * 64 + (l >> 4) * 16;
            bf16x8 ah = *(const bf16x8*)(Ah + aoff);
            bf16x8 alo = *(const bf16x8*)(Al + aoff);
            #pragma unroll
            for (int ct = 0; ct < 4; ++ct) {
                int boff = (ct * 16 + (l & 15)) * 144 + kk * 64 + (l >> 4) * 16;
                bf16x8 bh = *(const bf16x8*)(Bh + boff);
                bf16x8 bl = *(const bf16x8*)(Bl + boff);
                acc[ct] = __builtin_amdgcn_mfma_f32_16x16x32_bf16(ah, bh, acc[ct], 0, 0, 0);
                acc[ct] = __builtin_amdgcn_mfma_f32_16x16x32_bf16(alo, bh, acc[ct], 0, 0, 0);
                acc[ct] = __builtin_amdgcn_mfma_f32_16x16x32_bf16(ah, bl, acc[ct], 0, 0, 0);
            }
        }
    }
    int nrow = w * 16 + (l >> 4) * 4;
    #pragma unroll
    for (int ct = 0; ct < 4; ++ct)
        #pragma unroll
        for (int j = 0; j < 4; ++j) {
            long node = base + nrow + j;
            if (node < N_NODES) {
                int col = ct * 16 + (l & 15);
                xw1[node * 64 + col] = acc[ct][j];
                xw1b[node * 64 + col] = f2bf(acc[ct][j]);
            }
        }
}

// ---------- GEMM2 (MFMA, split-A, C^T): xw2_bf16[100000,320] = h @ W2 ----------
__global__ __launch_bounds__(512) void gemm2_mfma(const float* __restrict__ h,
        const uint16_t* __restrict__ w2T, uint16_t* __restrict__ xw2) {
    __shared__ __align__(16) char Bsm[320 * 144];
    int tid = threadIdx.x;
    int l = tid & 63, w = tid >> 6;
    long base = (long)blockIdx.x * 128;
    #pragma unroll
    for (int it = 0; it < 5; ++it) {
        int idx = tid + it * 512;
        int c = idx >> 3, kc = idx & 7;
        *(uint4*)(Bsm + c * 144 + kc * 16) = *(const uint4*)(w2T + (long)c * 64 + kc * 8);
    }
    long n0 = base + w * 16 + (l & 15);
    long nld = n0 < N_NODES ? n0 : N_NODES - 1;
    bf16x8 ah[2], alo[2];
    #pragma unroll
    for (int kk = 0; kk < 2; ++kk) {
        const float4* p = (const float4*)(h + nld * 64 + kk * 32 + (l >> 4) * 8);
        float4 f0 = p[0], f1 = p[1];
        float v[8] = {f0.x, f0.y, f0.z, f0.w, f1.x, f1.y, f1.z, f1.w};
        bf16x8 hv, lv;
        #pragma unroll
        for (int t = 0; t < 8; ++t) {
            uint16_t hh = f2bf(v[t]);
            hv[t] = (short)hh;
            lv[t] = (short)f2bf(v[t] - bfval(hh));
        }
        ah[kk] = hv; alo[kk] = lv;
    }
    __syncthreads();
    f32x4 acc[20];
    #pragma unroll
    for (int ct = 0; ct < 20; ++ct)
        #pragma unroll
        for (int j = 0; j < 4; ++j) acc[ct][j] = 0.f;
    #pragma unroll
    for (int ct = 0; ct < 20; ++ct) {
        #pragma unroll
        for (int kk = 0; kk < 2; ++kk) {
            bf16x8 b = *(const bf16x8*)(Bsm + (ct * 16 + (l & 15)) * 144 + kk * 64 + (l >> 4) * 16);
            acc[ct] = __builtin_amdgcn_mfma_f32_16x16x32_bf16(b, ah[kk], acc[ct], 0, 0, 0);
            acc[ct] = __builtin_amdgcn_mfma_f32_16x16x32_bf16(b, alo[kk], acc[ct], 0, 0, 0);
        }
    }
    if (n0 < N_NODES) {
        #pragma unroll
        for (int ct = 0; ct < 20; ++ct) {
            uint32_t d0 = f2bf(acc[ct][0]) | ((uint32_t)f2bf(acc[ct][1]) << 16);
            uint32_t d1 = f2bf(acc[ct][2]) | ((uint32_t)f2bf(acc[ct][3]) << 16);
            int cb = ct * 16 + (l >> 4) * 4;
            *(uint32_t*)(xw2 + n0 * 320 + cb) = d0;
            *(uint32_t*)(xw2 + n0 * 320 + cb + 2) = d1;
        }
    }
}

// ---------- CSR build (csr stores src*8) ----------
__global__ void hist_k(const int* __restrict__ dst, int* __restrict__ deg) {
    int e = blockIdx.x * blockDim.x + threadIdx.x;
    if (e < N_EDGES) atomicAdd(&deg[dst[e]], 1);
}

__global__ __launch_bounds__(512) void scan_a(const int* __restrict__ deg,
        int* __restrict__ offs, int* __restrict__ btot) {
    __shared__ int sh[512];
    int t = threadIdx.x;
    int g = blockIdx.x * 512 + t;
    int v = (g < N_NODES) ? deg[g] : 0;
    sh[t] = v;
    __syncthreads();
    #pragma unroll
    for (int o = 1; o < 512; o <<= 1) {
        int add = (t >= o) ? sh[t - o] : 0;
        __syncthreads();
        sh[t] += add;
        __syncthreads();
    }
    if (g < N_NODES) offs[g] = sh[t] - v;
    if (t == 511) btot[blockIdx.x] = sh[511];
}

__global__ __launch_bounds__(256) void scan_b(int* __restrict__ btot) {
    __shared__ int sh[256];
    int t = threadIdx.x;
    int v = (t < SCAN_NB) ? btot[t] : 0;
    sh[t] = v;
    __syncthreads();
    #pragma unroll
    for (int o = 1; o < 256; o <<= 1) {
        int add = (t >= o) ? sh[t - o] : 0;
        __syncthreads();
        sh[t] += add;
        __syncthreads();
    }
    if (t < SCAN_NB) btot[t] = sh[t] - v;
}

__global__ __launch_bounds__(512) void scan_c(int* __restrict__ offs,
        const int* __restrict__ btot, int* __restrict__ cursor) {
    int g = blockIdx.x * 512 + threadIdx.x;
    if (g < N_NODES) {
        int o = offs[g] + btot[blockIdx.x];
        offs[g] = o;
        cursor[g] = o;
    }
}

__global__ void scatter_k(const int* __restrict__ src, const int* __restrict__ dst,
        int* __restrict__ cursor, int* __restrict__ csr8) {
    int e = blockIdx.x * blockDim.x + threadIdx.x;
    if (e < N_EDGES) {
        int pos = atomicAdd(&cursor[dst[e]], 1);
        csr8[pos] = src[e] << 3;
    }
}

// ---------- conv1: head-per-lane; bf16 gathers from xw1b; fused al/ar epilogue ----------
__global__ __launch_bounds__(256) void conv1_node(const float* __restrict__ xw,
        const uint16_t* __restrict__ xwb,
        const int* __restrict__ offs, const int* __restrict__ deg,
        const int* __restrict__ csr8, const float* __restrict__ att_l,
        const float* __restrict__ att_r, const float* __restrict__ b1,
        const float* __restrict__ wl2, const float* __restrict__ wr2,
        float* __restrict__ hout, float* __restrict__ al, float* __restrict__ ar) {
    int wid = (blockIdx.x * blockDim.x + threadIdx.x) >> 6;
    if (wid >= N_NODES) return;
    int i = wid;
    int lane = threadIdx.x & 63;
    int g = lane >> 3, h = lane & 7;
    const float4* rowi = (const float4*)(xw + (long)i * 64 + h * 8);
    float4 xi0 = rowi[0], xi1 = rowi[1];
    f32x2 xip[4] = {{xi0.x, xi0.y}, {xi0.z, xi0.w}, {xi1.x, xi1.y}, {xi1.z, xi1.w}};
    const float4* alp4 = (const float4*)(att_l + h * 8);
    float4 t0 = alp4[0], t1 = alp4[1];
    f32x2 atlp[4] = {{t0.x, t0.y}, {t0.z, t0.w}, {t1.x, t1.y}, {t1.z, t1.w}};
    const float4* arp4 = (const float4*)(att_r + h * 8);
    float4 u0 = arp4[0], u1 = arp4[1];
    f32x2 atrp[4] = {{u0.x, u0.y}, {u0.z, u0.w}, {u1.x, u1.y}, {u1.z, u1.w}};
    f32x2 prp = xip[0] * atrp[0];
    prp += xip[1] * atrp[1];
    prp += xip[2] * atrp[2];
    prp += xip[3] * atrp[3];
    float pr = prp.x + prp.y;
    f32x2 accp[4] = {{0.f,0.f},{0.f,0.f},{0.f,0.f},{0.f,0.f}};
    float den = 0.f;

#define C1_EDGE(XJP) do { \
    f32x2 qdp = xip[0] * (XJP)[0]; \
    qdp += xip[1] * (XJP)[1]; \
    qdp += xip[2] * (XJP)[2]; \
    qdp += xip[3] * (XJP)[3]; \
    f32x2 qlp = (XJP)[0] * atlp[0]; \
    qlp += (XJP)[1] * atlp[1]; \
    qlp += (XJP)[2] * atlp[2]; \
    qlp += (XJP)[3] * atlp[3]; \
    float qd = qdp.x + qdp.y, ql = qlp.x + qlp.y; \
    float a = (ql + pr) * fast_rcp(1.0f + __expf(-qd)); \
    a = fmaxf(a, 0.2f * a); \
    float e = __expf(a); \
    den += e; \
    f32x2 ev = {e, e}; \
    accp[0] += ev * (XJP)[0]; \
    accp[1] += ev * (XJP)[1]; \
    accp[2] += ev * (XJP)[2]; \
    accp[3] += ev * (XJP)[3]; \
} while (0)

    if (g == 0) C1_EDGE(xip);   // self loop
    int off = offs[i], dg = deg[i];
    int k = g;
    for (; k + 8 < dg; k += 16) {
        int j0 = csr8[off + k], j1 = csr8[off + k + 8];
        uint4 q0 = *(const uint4*)(xwb + (long)j0 * 8 + h * 8);
        uint4 q1 = *(const uint4*)(xwb + (long)j1 * 8 + h * 8);
        f32x2 ap[4] = {{blo(q0.x), bhi(q0.x)}, {blo(q0.y), bhi(q0.y)},
                       {blo(q0.z), bhi(q0.z)}, {blo(q0.w), bhi(q0.w)}};
        f32x2 bp[4] = {{blo(q1.x), bhi(q1.x)}, {blo(q1.y), bhi(q1.y)},
                       {blo(q1.z), bhi(q1.z)}, {blo(q1.w), bhi(q1.w)}};
        C1_EDGE(ap);
        C1_EDGE(bp);
    }
    if (k < dg) {
        int j0 = csr8[off + k];
        uint4 q0 = *(const uint4*)(xwb + (long)j0 * 8 + h * 8);
        f32x2 ap[4] = {{blo(q0.x), bhi(q0.x)}, {blo(q0.y), bhi(q0.y)},
                       {blo(q0.z), bhi(q0.z)}, {blo(q0.w), bhi(q0.w)}};
        C1_EDGE(ap);
    }
#undef C1_EDGE

    float acc[8] = {accp[0].x, accp[0].y, accp[1].x, accp[1].y,
                    accp[2].x, accp[2].y, accp[3].x, accp[3].y};
    #pragma unroll
    for (int o = 8; o <= 32; o <<= 1) {
        #pragma unroll
        for (int t = 0; t < 8; ++t) acc[t] += __shfl_xor(acc[t], o);
        den += __shfl_xor(den, o);
    }
    // all lanes now hold the full sums for head h -> ELU'd h-row slice
    float inv = fast_rcp(den + 1e-16f);
    const float4* bp4 = (const float4*)(b1 + h * 8);
    float4 c0 = bp4[0], c1 = bp4[1];
    float bias[8] = {c0.x, c0.y, c0.z, c0.w, c1.x, c1.y, c1.z, c1.w};
    float ov[8];
    #pragma unroll
    for (int t = 0; t < 8; ++t) {
        float v = acc[t] * inv + bias[t];
        ov[t] = v > 0.f ? v : __expf(v) - 1.0f;
    }
    if (g == 0) {
        float4* po = (float4*)(hout + (long)i * 64 + h * 8);
        po[0] = make_float4(ov[0], ov[1], ov[2], ov[3]);
        po[1] = make_float4(ov[4], ov[5], ov[6], ov[7]);
    }
    // fused al/ar: lane (g,h) dots its 8 h-vals (dims h*8..) with wl2[head=g][h*8..],
    // reduce over h (xor 1,2,4); h==0 lanes write al/ar[i*8 + g]
    {
        const float4* wlp = (const float4*)(wl2 + g * 64 + h * 8);
        float4 w0 = wlp[0], w1 = wlp[1];
        const float4* wrp = (const float4*)(wr2 + g * 64 + h * 8);
        float4 r0 = wrp[0], r1 = wrp[1];
        float sl = ov[0]*w0.x + ov[1]*w0.y + ov[2]*w0.z + ov[3]*w0.w
                 + ov[4]*w1.x + ov[5]*w1.y + ov[6]*w1.z + ov[7]*w1.w;
        float sr = ov[0]*r0.x + ov[1]*r0.y + ov[2]*r0.z + ov[3]*r0.w
                 + ov[4]*r1.x + ov[5]*r1.y + ov[6]*r1.z + ov[7]*r1.w;
        #pragma unroll
        for (int o = 1; o <= 4; o <<= 1) {
            sl += __shfl_xor(sl, o);
            sr += __shfl_xor(sr, o);
        }
        if (h == 0) {
            al[i * 8 + g] = sl;
            ar[i * 8 + g] = sr;
        }
    }
}

// ---------- conv2: R1 structure (x-space), 2-deep prefetch, DPP quad reduce ----------
__device__ __forceinline__ int fidx(const int* __restrict__ csr8, int pos, int valid) {
    int p = pos < N_EDGES ? pos : N_EDGES - 1;
    int j = csr8[p];
    return valid ? j : 0;
}

__global__ __launch_bounds__(256) void conv2_node(const uint16_t* __restrict__ xw,
        const int* __restrict__ offs, const int* __restrict__ deg,
        const int* __restrict__ csr8, const float* __restrict__ al,
        const float* __restrict__ ar, const float* __restrict__ b2,
        float* __restrict__ out) {
    if (blockIdx.x == 0 && threadIdx.x == 0) out[(long)N_NODES * 40] = 0.0f;  // att_loss
    int wid = (blockIdx.x * blockDim.x + threadIdx.x) >> 6;
    if (wid >= N_NODES) return;
    int i = wid;
    int lane = threadIdx.x & 63;
    int half = lane >> 5, l = lane & 31;
    int h = l >> 2, q = l & 3;
    const uint32_t* xwd = (const uint32_t*)xw;
    // lane q of head h owns dwords [20h+4q, +4) (16B aligned) and dword 20h+16+q
    unsigned lq4 = 20u * (unsigned)h + 4u * (unsigned)q;
    unsigned lq1 = 20u * (unsigned)h + 16u + (unsigned)q;

    f32x2 xip[5];
    {
        const uint32_t* rowi = xwd + (unsigned)i * 160u;
        uint4 qi = *(const uint4*)(rowi + lq4);
        uint32_t ti = rowi[lq1];
        xip[0] = (f32x2){blo(qi.x), bhi(qi.x)};
        xip[1] = (f32x2){blo(qi.y), bhi(qi.y)};
        xip[2] = (f32x2){blo(qi.z), bhi(qi.z)};
        xip[3] = (f32x2){blo(qi.w), bhi(qi.w)};
        xip[4] = (f32x2){blo(ti),   bhi(ti)};
    }
    float ari = ar[i * 8 + h];
    f32x2 accp[5] = {{0.f,0.f},{0.f,0.f},{0.f,0.f},{0.f,0.f},{0.f,0.f}};
    float den = 0.f;

#define C2_CORE(ALJ, XJP) do { \
    f32x2 pdp = xip[0] * (XJP)[0]; \
    pdp += xip[1] * (XJP)[1]; \
    pdp += xip[2] * (XJP)[2]; \
    pdp += xip[3] * (XJP)[3]; \
    pdp += xip[4] * (XJP)[4]; \
    float pd = pdp.x + pdp.y; \
    pd = dpp_xadd1(pd); \
    pd = dpp_xadd2(pd); \
    float a = ((ALJ) + ari) * fast_rcp(1.0f + __expf(-pd)); \
    a = fmaxf(a, 0.2f * a); \
    float e = __expf(a); \
    den += e; \
    f32x2 ev = {e, e}; \
    accp[0] += ev * (XJP)[0]; \
    accp[1] += ev * (XJP)[1]; \
    accp[2] += ev * (XJP)[2]; \
    accp[3] += ev * (XJP)[3]; \
    accp[4] += ev * (XJP)[4]; \
} while (0)

#define C2_UNPACK(DST, U) do { \
    _Pragma("unroll") \
    for (int t = 0; t < 5; ++t) (DST)[t] = (f32x2){blo((U)[t]), bhi((U)[t])}; \
} while (0)

#define C2_FETCH(J, BUF, ALV) do { \
    const uint32_t* _r = xwd + (unsigned)(J) * 20u; \
    uint4 _q = *(const uint4*)(_r + lq4); \
    (BUF)[0] = _q.x; (BUF)[1] = _q.y; (BUF)[2] = _q.z; (BUF)[3] = _q.w; \
    (BUF)[4] = _r[lq1]; \
    (ALV) = al[(J) + h]; \
} while (0)

    if (half == 0) C2_CORE(al[i * 8 + h], xip);   // self loop
    int off = offs[i], dg = deg[i];

    int k = half;
    int v0 = (k < dg), v1 = (k + 2 < dg);
    int j0 = fidx(csr8, off + k, v0);
    int j1 = fidx(csr8, off + k + 2, v1);
    uint32_t cA[5], cB[5], dA[5], dB[5];
    float alA, alB, alC, alD;
    C2_FETCH(j0, cA, alA);
    C2_FETCH(j1, cB, alB);
    while (v0) {
        // prefetch pair (k+4, k+6)
        int k4 = k + 4;
        int w0 = (k4 < dg), w1 = (k4 + 2 < dg);
        int m0 = fidx(csr8, off + k4, w0);
        int m1 = fidx(csr8, off + k4 + 2, w1);
        C2_FETCH(m0, dA, alC);
        C2_FETCH(m1, dB, alD);
        // compute current pair
        { f32x2 xj[5]; C2_UNPACK(xj, cA); C2_CORE(alA, xj); }
        if (v1) { f32x2 xj[5]; C2_UNPACK(xj, cB); C2_CORE(alB, xj); }
        if (!w0) break;
        // prefetch pair (k+8, k+10)
        int k8 = k + 8;
        v0 = (k8 < dg); v1 = (k8 + 2 < dg);
        int p0 = fidx(csr8, off + k8, v0);
        int p1 = fidx(csr8, off + k8 + 2, v1);
        C2_FETCH(p0, cA, alA);
        C2_FETCH(p1, cB, alB);
        // compute prefetched pair
        { f32x2 xj[5]; C2_UNPACK(xj, dA); C2_CORE(alC, xj); }
        if (w1) { f32x2 xj[5]; C2_UNPACK(xj, dB); C2_CORE(alD, xj); }
        k = k8;
    }
#undef C2_CORE
#undef C2_UNPACK
#undef C2_FETCH

    float acc[10] = {accp[0].x, accp[0].y, accp[1].x, accp[1].y, accp[2].x,
                     accp[2].y, accp[3].x, accp[3].y, accp[4].x, accp[4].y};
    #pragma unroll
    for (int t = 0; t < 10; ++t) acc[t] += __shfl_xor(acc[t], 32);
    den += __shfl_xor(den, 32);
    float inv = 0.125f * fast_rcp(den + 1e-16f);
    #pragma unroll
    for (int t = 0; t < 10; ++t) acc[t] *= inv;
    #pragma unroll
    for (int o = 4; o <= 16; o <<= 1) {
        #pragma unroll
        for (int t = 0; t < 10; ++t) acc[t] += __shfl_xor(acc[t], o);
    }
    // fused +b2 and log_softmax; lane q holds channels {8q..8q+7, 32+2q, 33+2q}
    #pragma unroll
    for (int t = 0; t < 8; ++t) acc[t] += b2[8 * q + t];
    acc[8] += b2[32 + 2 * q];
    acc[9] += b2[33 + 2 * q];
    float mx = acc[0];
    #pragma unroll
    for (int t = 1; t < 10; ++t) mx = fmaxf(mx, acc[t]);
    mx = fmaxf(mx, __shfl_xor(mx, 1));
    mx = fmaxf(mx, __shfl_xor(mx, 2));
    float s = 0.f;
    #pragma unroll
    for (int t = 0; t < 10; ++t) s += __expf(acc[t] - mx);
    s += __shfl_xor(s, 1);
    s += __shfl_xor(s, 2);
    float lse = mx + __logf(s);
    if (lane < 4) {
        float4* po = (float4*)(out + (long)i * 40 + 8 * q);
        po[0] = make_float4(acc[0] - lse, acc[1] - lse, acc[2] - lse, acc[3] - lse);
        po[1] = make_float4(acc[4] - lse, acc[5] - lse, acc[6] - lse, acc[7] - lse);
        float2* pt = (float2*)(out + (long)i * 40 + 32 + 2 * q);
        *pt = make_float2(acc[8] - lse, acc[9] - lse);
    }
}

extern "C" void kernel_launch(void* const* d_in, const int* in_sizes, int n_in,
                              void* d_out, int out_size, void* d_ws, size_t ws_size,
                              hipStream_t stream) {
    const float* x      = (const float*)d_in[0];
    const int*   ei     = (const int*)d_in[1];
    const float* W1     = (const float*)d_in[2];
    const float* att_l1 = (const float*)d_in[3];
    const float* att_r1 = (const float*)d_in[4];
    const float* b1     = (const float*)d_in[5];
    const float* W2     = (const float*)d_in[6];
    const float* att_l2 = (const float*)d_in[7];
    const float* att_r2 = (const float*)d_in[8];
    const float* b2     = (const float*)d_in[9];
    const int* src = ei;
    const int* dst = ei + N_EDGES;
    float* out = (float*)d_out;

    char* ws = (char*)d_ws;
    float*    xw1    = (float*)(ws + 0);            // 25.6 MB
    float*    hbuf   = (float*)(ws + 25600000);     // 25.6 MB (f32 h)
    uint16_t* xw2b   = (uint16_t*)(ws + 51200000);  // 64 MB (bf16)
    // xw1b aliases the first 12.8 MB of xw2b: dead before gemm2 writes xw2b
    uint16_t* xw1b   = (uint16_t*)(ws + 51200000);  // 12.8 MB (dead after conv1)
    float*    al     = (float*)(ws + 115200000);    // 3.2 MB
    float*    ar     = (float*)(ws + 118400000);    // 3.2 MB
    int*      deg    = (int*)(ws + 121600000);      // 400 KB
    int*      offs   = (int*)(ws + 122000000);      // 400 KB
    int*      cursor = (int*)(ws + 122400000);      // 400 KB
    int*      btot   = (int*)(ws + 122800000);      // 1 KB
    int*      csr8   = (int*)(ws + 122801024);      // 6.4 MB
    uint16_t* w1hi   = (uint16_t*)(ws + 129201024); // 64 KB
    uint16_t* w1lo   = (uint16_t*)(ws + 129266560); // 64 KB
    uint16_t* w2T    = (uint16_t*)(ws + 129332096); // 40 KB
    float*    wl2    = (float*)(ws + 129373056);    // 2 KB
    float*    wr2    = (float*)(ws + 129375104);    // 2 KB -> ~129.4 MB total

    hipMemsetAsync(deg, 0, (size_t)N_NODES * 4, stream);

    // fused weight prep (blocks: 0-7 cvt_w1 | 8 wvec | 9 cvt_w2)
    prep_k<<<10, 512, 0, stream>>>(W1, W2, att_l2, att_r2,
                                   w1hi, w1lo, wl2, wr2, w2T);

    // CSR build (dst-sorted adjacency; csr stores src*8)
    hist_k<<<6250, 256, 0, stream>>>(dst, deg);
    scan_a<<<SCAN_NB, 512, 0, stream>>>(deg, offs, btot);
    scan_b<<<1, 256, 0, stream>>>(btot);
    scan_c<<<SCAN_NB, 512, 0, stream>>>(offs, btot, cursor);
    scatter_k<<<6250, 256, 0, stream>>>(src, dst, cursor, csr8);

    // conv1 (bf16 gathers; al/ar fused into epilogue -> node_att2h eliminated)
    gemm1_mfma<<<782, 512, 0, stream>>>(x, w1hi, w1lo, xw1, xw1b);
    conv1_node<<<25000, 256, 0, stream>>>(xw1, xw1b, offs, deg, csr8,
                                          att_l1, att_r1, b1, wl2, wr2,
                                          hbuf, al, ar);

    // conv2 (log_softmax fused into conv2_node)
    gemm2_mfma<<<782, 512, 0, stream>>>(hbuf, w2T, xw2b);
    conv2_node<<<25000, 256, 0, stream>>>(xw2b, offs, deg, csr8, al, ar, b2, out);
}

// Round 9
// 463.394 us; speedup vs baseline: 1.2746x; 1.1370x over previous
//
#include <hip/hip_runtime.h>
#include <cstdint>

#define N_NODES 100000
#define N_EDGES 1600000
#define SCAN_NB 196   // ceil(100000/512)

typedef short bf16x8 __attribute__((ext_vector_type(8)));
typedef float f32x4 __attribute__((ext_vector_type(4)));
typedef float f32x2 __attribute__((ext_vector_type(2)));   // -> v_pk_fma_f32

// ---------- bf16 helpers ----------
__device__ __forceinline__ uint16_t f2bf(float f) {
    uint32_t b = __float_as_uint(f);
    return (uint16_t)((b + 0x7fffu + ((b >> 16) & 1u)) >> 16);  // RNE
}
__device__ __forceinline__ float bfval(uint16_t u) {
    return __uint_as_float(((uint32_t)u) << 16);
}
__device__ __forceinline__ float blo(uint32_t u) { return __uint_as_float(u << 16); }
__device__ __forceinline__ float bhi(uint32_t u) { return __uint_as_float(u & 0xffff0000u); }

// ---------- fast math helpers ----------
__device__ __forceinline__ float fast_rcp(float x) { return __builtin_amdgcn_rcpf(x); }
// in-quad butterfly adds via DPP quad_perm
__device__ __forceinline__ float dpp_xadd1(float x) {
    int s = __builtin_amdgcn_update_dpp(0, __float_as_int(x), 0xB1, 0xF, 0xF, true); // [1,0,3,2]
    return x + __int_as_float(s);
}
__device__ __forceinline__ float dpp_xadd2(float x) {
    int s = __builtin_amdgcn_update_dpp(0, __float_as_int(x), 0x4E, 0xF, 0xF, true); // [2,3,0,1]
    return x + __int_as_float(s);
}

// ---------- prep (blocks 0-9) fused with hist (blocks 10..3134) ----------
__global__ __launch_bounds__(512) void prep_hist_k(const float* __restrict__ W1,
        const float* __restrict__ W2, const float* __restrict__ attl,
        const float* __restrict__ attr,
        uint16_t* __restrict__ w1hi, uint16_t* __restrict__ w1lo,
        float* __restrict__ wl2, float* __restrict__ wr2,
        uint16_t* __restrict__ w2T,
        const int* __restrict__ dst, int* __restrict__ deg) {
    int b = blockIdx.x, tid = threadIdx.x;
    if (b >= 10) {                     // hist: 3125 blocks x 512 = 1.6M edges
        int e = (b - 10) * 512 + tid;
        if (e < N_EDGES) atomicAdd(&deg[dst[e]], 1);
        return;
    }
    if (b < 8) {                       // cvt_w1: 4096 work-items (split bf16 hi/lo)
        int gid = b * 512 + tid;
        int c = gid & 63, kg = gid >> 6;
        uint32_t dh[4], dl[4];
        #pragma unroll
        for (int t = 0; t < 4; ++t) {
            float v0 = W1[(kg * 8 + 2 * t) * 64 + c];
            float v1 = W1[(kg * 8 + 2 * t + 1) * 64 + c];
            uint16_t h0 = f2bf(v0), h1 = f2bf(v1);
            uint16_t l0 = f2bf(v0 - bfval(h0)), l1 = f2bf(v1 - bfval(h1));
            dh[t] = h0 | ((uint32_t)h1 << 16);
            dl[t] = l0 | ((uint32_t)l1 << 16);
        }
        *(uint4*)(w1hi + (long)c * 512 + kg * 8) = make_uint4(dh[0], dh[1], dh[2], dh[3]);
        *(uint4*)(w1lo + (long)c * 512 + kg * 8) = make_uint4(dl[0], dl[1], dl[2], dl[3]);
    } else if (b == 8) {               // wvec: wl2[h][64] = W2_h @ att_l2_h
        int h = tid >> 6, k = tid & 63;
        float sl = 0.f, sr = 0.f;
        #pragma unroll 8
        for (int c = 0; c < 40; ++c) {
            float w = W2[k * 320 + h * 40 + c];
            sl += w * attl[h * 40 + c];
            sr += w * attr[h * 40 + c];
        }
        wl2[tid] = sl; wr2[tid] = sr;
    } else {                           // cvt_w2: col-major [col:320][k:64] bf16
        int c = tid;
        if (c < 320) {
            for (int kg = 0; kg < 8; ++kg) {
                uint32_t d[4];
                #pragma unroll
                for (int t = 0; t < 4; ++t) {
                    float v0 = W2[(kg * 8 + 2 * t) * 320 + c];
                    float v1 = W2[(kg * 8 + 2 * t + 1) * 320 + c];
                    d[t] = f2bf(v0) | ((uint32_t)f2bf(v1) << 16);
                }
                *(uint4*)(w2T + (long)c * 64 + kg * 8) = make_uint4(d[0], d[1], d[2], d[3]);
            }
        }
    }
}

// ---------- scans (offs = block-local exclusive prefix; btot = block offsets) ----------
__global__ __launch_bounds__(512) void scan_a(const int* __restrict__ deg,
        int* __restrict__ offs, int* __restrict__ btot) {
    __shared__ int sh[512];
    int t = threadIdx.x;
    int g = blockIdx.x * 512 + t;
    int v = (g < N_NODES) ? deg[g] : 0;
    sh[t] = v;
    __syncthreads();
    #pragma unroll
    for (int o = 1; o < 512; o <<= 1) {
        int add = (t >= o) ? sh[t - o] : 0;
        __syncthreads();
        sh[t] += add;
        __syncthreads();
    }
    if (g < N_NODES) offs[g] = sh[t] - v;
    if (t == 511) btot[blockIdx.x] = sh[511];
}

__global__ __launch_bounds__(256) void scan_b(int* __restrict__ btot) {
    __shared__ int sh[256];
    int t = threadIdx.x;
    int v = (t < SCAN_NB) ? btot[t] : 0;
    sh[t] = v;
    __syncthreads();
    #pragma unroll
    for (int o = 1; o < 256; o <<= 1) {
        int add = (t >= o) ? sh[t - o] : 0;
        __syncthreads();
        sh[t] += add;
        __syncthreads();
    }
    if (t < SCAN_NB) btot[t] = sh[t] - v;
}

// ---------- GEMM1 (blocks 0..781) fused with scatter (blocks 782..2344) ----------
// scatter: pos = btot[dst>>9] + atomicAdd(&offs[dst],1)  (offs -> end offsets;
//          conv kernels recompute start = btot[i>>9] + offs[i] - deg[i])
__global__ __launch_bounds__(512) void gemm1_scatter(const float* __restrict__ x,
        const uint16_t* __restrict__ w1hi, const uint16_t* __restrict__ w1lo,
        float* __restrict__ xw1, uint16_t* __restrict__ xw1b,
        const int* __restrict__ src, const int* __restrict__ dst,
        int* __restrict__ offs, const int* __restrict__ btot,
        int* __restrict__ csr8) {
    __shared__ __align__(16) char Ah[128 * 144];
    __shared__ __align__(16) char Al[128 * 144];
    __shared__ __align__(16) char Bh[64 * 144];
    __shared__ __align__(16) char Bl[64 * 144];
    int tid = threadIdx.x;
    if (blockIdx.x >= 782) {           // scatter: 1563 blocks x 512 x 2 edges
        int base = (blockIdx.x - 782) * 1024 + tid;
        #pragma unroll
        for (int r = 0; r < 2; ++r) {
            int e = base + r * 512;
            if (e < N_EDGES) {
                int d = dst[e];
                int old = atomicAdd(&offs[d], 1);
                csr8[btot[d >> 9] + old] = src[e] << 3;
            }
        }
        return;
    }
    int l = tid & 63, w = tid >> 6;
    long base = (long)blockIdx.x * 128;
    f32x4 acc[4];
    #pragma unroll
    for (int ct = 0; ct < 4; ++ct)
        #pragma unroll
        for (int j = 0; j < 4; ++j) acc[ct][j] = 0.f;

    for (int kb = 0; kb < 512; kb += 64) {
        __syncthreads();
        #pragma unroll
        for (int it = 0; it < 2; ++it) {
            int idx = tid + it * 512;
            int row = idx >> 3, kc = idx & 7;
            long r = base + row; if (r >= N_NODES) r = N_NODES - 1;
            const float4* p = (const float4*)(x + r * 512 + kb + kc * 8);
            float4 f0 = p[0], f1 = p[1];
            float v[8] = {f0.x, f0.y, f0.z, f0.w, f1.x, f1.y, f1.z, f1.w};
            uint32_t dh[4], dl[4];
            #pragma unroll
            for (int t = 0; t < 4; ++t) {
                uint16_t h0 = f2bf(v[2 * t]),     h1 = f2bf(v[2 * t + 1]);
                uint16_t l0 = f2bf(v[2 * t] - bfval(h0));
                uint16_t l1 = f2bf(v[2 * t + 1] - bfval(h1));
                dh[t] = h0 | ((uint32_t)h1 << 16);
                dl[t] = l0 | ((uint32_t)l1 << 16);
            }
            *(uint4*)(Ah + row * 144 + kc * 16) = make_uint4(dh[0], dh[1], dh[2], dh[3]);
            *(uint4*)(Al + row * 144 + kc * 16) = make_uint4(dl[0], dl[1], dl[2], dl[3]);
        }
        {
            int c = tid >> 3, kc = tid & 7;
            *(uint4*)(Bh + c * 144 + kc * 16) =
                *(const uint4*)(w1hi + (long)c * 512 + kb + kc * 8);
            *(uint4*)(Bl + c * 144 + kc * 16) =
                *(const uint4*)(w1lo + (long)c * 512 + kb + kc * 8);
        }
        __syncthreads();
        #pragma unroll
        for (int kk = 0; kk < 2; ++kk) {
            int aoff = (w * 16 + (l & 15)) * 144 + kk * 64 + (l >> 4) * 16;
            bf16x8 ah = *(const bf16x8*)(Ah + aoff);
            bf16x8 alo = *(const bf16x8*)(Al + aoff);
            #pragma unroll
            for (int ct = 0; ct < 4; ++ct) {
                int boff = (ct * 16 + (l & 15)) * 144 + kk * 64 + (l >> 4) * 16;
                bf16x8 bh = *(const bf16x8*)(Bh + boff);
                bf16x8 bl = *(const bf16x8*)(Bl + boff);
                acc[ct] = __builtin_amdgcn_mfma_f32_16x16x32_bf16(ah, bh, acc[ct], 0, 0, 0);
                acc[ct] = __builtin_amdgcn_mfma_f32_16x16x32_bf16(alo, bh, acc[ct], 0, 0, 0);
                acc[ct] = __builtin_amdgcn_mfma_f32_16x16x32_bf16(ah, bl, acc[ct], 0, 0, 0);
            }
        }
    }
    int nrow = w * 16 + (l >> 4) * 4;
    #pragma unroll
    for (int ct = 0; ct < 4; ++ct)
        #pragma unroll
        for (int j = 0; j < 4; ++j) {
            long node = base + nrow + j;
            if (node < N_NODES) {
                int col = ct * 16 + (l & 15);
                xw1[node * 64 + col] = acc[ct][j];
                xw1b[node * 64 + col] = f2bf(acc[ct][j]);
            }
        }
}

// ---------- GEMM2 (MFMA, split-A, C^T): xw2_bf16[100000,320] = h @ W2 ----------
__global__ __launch_bounds__(512) void gemm2_mfma(const float* __restrict__ h,
        const uint16_t* __restrict__ w2T, uint16_t* __restrict__ xw2) {
    __shared__ __align__(16) char Bsm[320 * 144];
    int tid = threadIdx.x;
    int l = tid & 63, w = tid >> 6;
    long base = (long)blockIdx.x * 128;
    #pragma unroll
    for (int it = 0; it < 5; ++it) {
        int idx = tid + it * 512;
        int c = idx >> 3, kc = idx & 7;
        *(uint4*)(Bsm + c * 144 + kc * 16) = *(const uint4*)(w2T + (long)c * 64 + kc * 8);
    }
    long n0 = base + w * 16 + (l & 15);
    long nld = n0 < N_NODES ? n0 : N_NODES - 1;
    bf16x8 ah[2], alo[2];
    #pragma unroll
    for (int kk = 0; kk < 2; ++kk) {
        const float4* p = (const float4*)(h + nld * 64 + kk * 32 + (l >> 4) * 8);
        float4 f0 = p[0], f1 = p[1];
        float v[8] = {f0.x, f0.y, f0.z, f0.w, f1.x, f1.y, f1.z, f1.w};
        bf16x8 hv, lv;
        #pragma unroll
        for (int t = 0; t < 8; ++t) {
            uint16_t hh = f2bf(v[t]);
            hv[t] = (short)hh;
            lv[t] = (short)f2bf(v[t] - bfval(hh));
        }
        ah[kk] = hv; alo[kk] = lv;
    }
    __syncthreads();
    f32x4 acc[20];
    #pragma unroll
    for (int ct = 0; ct < 20; ++ct)
        #pragma unroll
        for (int j = 0; j < 4; ++j) acc[ct][j] = 0.f;
    #pragma unroll
    for (int ct = 0; ct < 20; ++ct) {
        #pragma unroll
        for (int kk = 0; kk < 2; ++kk) {
            bf16x8 b = *(const bf16x8*)(Bsm + (ct * 16 + (l & 15)) * 144 + kk * 64 + (l >> 4) * 16);
            acc[ct] = __builtin_amdgcn_mfma_f32_16x16x32_bf16(b, ah[kk], acc[ct], 0, 0, 0);
            acc[ct] = __builtin_amdgcn_mfma_f32_16x16x32_bf16(b, alo[kk], acc[ct], 0, 0, 0);
        }
    }
    if (n0 < N_NODES) {
        #pragma unroll
        for (int ct = 0; ct < 20; ++ct) {
            uint32_t d0 = f2bf(acc[ct][0]) | ((uint32_t)f2bf(acc[ct][1]) << 16);
            uint32_t d1 = f2bf(acc[ct][2]) | ((uint32_t)f2bf(acc[ct][3]) << 16);
            int cb = ct * 16 + (l >> 4) * 4;
            *(uint32_t*)(xw2 + n0 * 320 + cb) = d0;
            *(uint32_t*)(xw2 + n0 * 320 + cb + 2) = d1;
        }
    }
}

// ---------- conv1: head-per-lane; bf16 gathers from xw1b; fused al/ar epilogue ----------
__global__ __launch_bounds__(256) void conv1_node(const float* __restrict__ xw,
        const uint16_t* __restrict__ xwb,
        const int* __restrict__ offs, const int* __restrict__ deg,
        const int* __restrict__ btot,
        const int* __restrict__ csr8, const float* __restrict__ att_l,
        const float* __restrict__ att_r, const float* __restrict__ b1,
        const float* __restrict__ wl2, const float* __restrict__ wr2,
        float* __restrict__ hout, float* __restrict__ al, float* __restrict__ ar) {
    int wid = (blockIdx.x * blockDim.x + threadIdx.x) >> 6;
    if (wid >= N_NODES) return;
    int i = wid;
    int lane = threadIdx.x & 63;
    int g = lane >> 3, h = lane & 7;
    const float4* rowi = (const float4*)(xw + (long)i * 64 + h * 8);
    float4 xi0 = rowi[0], xi1 = rowi[1];
    f32x2 xip[4] = {{xi0.x, xi0.y}, {xi0.z, xi0.w}, {xi1.x, xi1.y}, {xi1.z, xi1.w}};
    const float4* alp4 = (const float4*)(att_l + h * 8);
    float4 t0 = alp4[0], t1 = alp4[1];
    f32x2 atlp[4] = {{t0.x, t0.y}, {t0.z, t0.w}, {t1.x, t1.y}, {t1.z, t1.w}};
    const float4* arp4 = (const float4*)(att_r + h * 8);
    float4 u0 = arp4[0], u1 = arp4[1];
    f32x2 atrp[4] = {{u0.x, u0.y}, {u0.z, u0.w}, {u1.x, u1.y}, {u1.z, u1.w}};
    f32x2 prp = xip[0] * atrp[0];
    prp += xip[1] * atrp[1];
    prp += xip[2] * atrp[2];
    prp += xip[3] * atrp[3];
    float pr = prp.x + prp.y;
    f32x2 accp[4] = {{0.f,0.f},{0.f,0.f},{0.f,0.f},{0.f,0.f}};
    float den = 0.f;

#define C1_EDGE(XJP) do { \
    f32x2 qdp = xip[0] * (XJP)[0]; \
    qdp += xip[1] * (XJP)[1]; \
    qdp += xip[2] * (XJP)[2]; \
    qdp += xip[3] * (XJP)[3]; \
    f32x2 qlp = (XJP)[0] * atlp[0]; \
    qlp += (XJP)[1] * atlp[1]; \
    qlp += (XJP)[2] * atlp[2]; \
    qlp += (XJP)[3] * atlp[3]; \
    float qd = qdp.x + qdp.y, ql = qlp.x + qlp.y; \
    float a = (ql + pr) * fast_rcp(1.0f + __expf(-qd)); \
    a = fmaxf(a, 0.2f * a); \
    float e = __expf(a); \
    den += e; \
    f32x2 ev = {e, e}; \
    accp[0] += ev * (XJP)[0]; \
    accp[1] += ev * (XJP)[1]; \
    accp[2] += ev * (XJP)[2]; \
    accp[3] += ev * (XJP)[3]; \
} while (0)

    if (g == 0) C1_EDGE(xip);   // self loop
    int dg = deg[i];
    int off = btot[i >> 9] + offs[i] - dg;   // offs holds end offsets post-scatter
    int k = g;
    for (; k + 8 < dg; k += 16) {
        int j0 = csr8[off + k], j1 = csr8[off + k + 8];
        uint4 q0 = *(const uint4*)(xwb + (long)j0 * 8 + h * 8);
        uint4 q1 = *(const uint4*)(xwb + (long)j1 * 8 + h * 8);
        f32x2 ap[4] = {{blo(q0.x), bhi(q0.x)}, {blo(q0.y), bhi(q0.y)},
                       {blo(q0.z), bhi(q0.z)}, {blo(q0.w), bhi(q0.w)}};
        f32x2 bp[4] = {{blo(q1.x), bhi(q1.x)}, {blo(q1.y), bhi(q1.y)},
                       {blo(q1.z), bhi(q1.z)}, {blo(q1.w), bhi(q1.w)}};
        C1_EDGE(ap);
        C1_EDGE(bp);
    }
    if (k < dg) {
        int j0 = csr8[off + k];
        uint4 q0 = *(const uint4*)(xwb + (long)j0 * 8 + h * 8);
        f32x2 ap[4] = {{blo(q0.x), bhi(q0.x)}, {blo(q0.y), bhi(q0.y)},
                       {blo(q0.z), bhi(q0.z)}, {blo(q0.w), bhi(q0.w)}};
        C1_EDGE(ap);
    }
#undef C1_EDGE

    float acc[8] = {accp[0].x, accp[0].y, accp[1].x, accp[1].y,
                    accp[2].x, accp[2].y, accp[3].x, accp[3].y};
    #pragma unroll
    for (int o = 8; o <= 32; o <<= 1) {
        #pragma unroll
        for (int t = 0; t < 8; ++t) acc[t] += __shfl_xor(acc[t], o);
        den += __shfl_xor(den, o);
    }
    // all lanes now hold the full sums for head h -> ELU'd h-row slice
    float inv = fast_rcp(den + 1e-16f);
    const float4* bp4 = (const float4*)(b1 + h * 8);
    float4 c0 = bp4[0], c1 = bp4[1];
    float bias[8] = {c0.x, c0.y, c0.z, c0.w, c1.x, c1.y, c1.z, c1.w};
    float ov[8];
    #pragma unroll
    for (int t = 0; t < 8; ++t) {
        float v = acc[t] * inv + bias[t];
        ov[t] = v > 0.f ? v : __expf(v) - 1.0f;
    }
    if (g == 0) {
        float4* po = (float4*)(hout + (long)i * 64 + h * 8);
        po[0] = make_float4(ov[0], ov[1], ov[2], ov[3]);
        po[1] = make_float4(ov[4], ov[5], ov[6], ov[7]);
    }
    // fused al/ar: lane (g,h) dots its 8 h-vals with wl2[head=g][h*8..], reduce over h
    {
        const float4* wlp = (const float4*)(wl2 + g * 64 + h * 8);
        float4 w0 = wlp[0], w1 = wlp[1];
        const float4* wrp = (const float4*)(wr2 + g * 64 + h * 8);
        float4 r0 = wrp[0], r1 = wrp[1];
        float sl = ov[0]*w0.x + ov[1]*w0.y + ov[2]*w0.z + ov[3]*w0.w
                 + ov[4]*w1.x + ov[5]*w1.y + ov[6]*w1.z + ov[7]*w1.w;
        float sr = ov[0]*r0.x + ov[1]*r0.y + ov[2]*r0.z + ov[3]*r0.w
                 + ov[4]*r1.x + ov[5]*r1.y + ov[6]*r1.z + ov[7]*r1.w;
        #pragma unroll
        for (int o = 1; o <= 4; o <<= 1) {
            sl += __shfl_xor(sl, o);
            sr += __shfl_xor(sr, o);
        }
        if (h == 0) {
            al[i * 8 + g] = sl;
            ar[i * 8 + g] = sr;
        }
    }
}

// ---------- conv2: R1 structure (x-space), 2-deep prefetch, DPP quad reduce ----------
__device__ __forceinline__ int fidx(const int* __restrict__ csr8, int pos, int valid) {
    int p = pos < N_EDGES ? pos : N_EDGES - 1;
    int j = csr8[p];
    return valid ? j : 0;
}

__global__ __launch_bounds__(256) void conv2_node(const uint16_t* __restrict__ xw,
        const int* __restrict__ offs, const int* __restrict__ deg,
        const int* __restrict__ btot,
        const int* __restrict__ csr8, const float* __restrict__ al,
        const float* __restrict__ ar, const float* __restrict__ b2,
        float* __restrict__ out) {
    if (blockIdx.x == 0 && threadIdx.x == 0) out[(long)N_NODES * 40] = 0.0f;  // att_loss
    int wid = (blockIdx.x * blockDim.x + threadIdx.x) >> 6;
    if (wid >= N_NODES) return;
    int i = wid;
    int lane = threadIdx.x & 63;
    int half = lane >> 5, l = lane & 31;
    int h = l >> 2, q = l & 3;
    const uint32_t* xwd = (const uint32_t*)xw;
    // lane q of head h owns dwords [20h+4q, +4) (16B aligned) and dword 20h+16+q
    unsigned lq4 = 20u * (unsigned)h + 4u * (unsigned)q;
    unsigned lq1 = 20u * (unsigned)h + 16u + (unsigned)q;

    f32x2 xip[5];
    {
        const uint32_t* rowi = xwd + (unsigned)i * 160u;
        uint4 qi = *(const uint4*)(rowi + lq4);
        uint32_t ti = rowi[lq1];
        xip[0] = (f32x2){blo(qi.x), bhi(qi.x)};
        xip[1] = (f32x2){blo(qi.y), bhi(qi.y)};
        xip[2] = (f32x2){blo(qi.z), bhi(qi.z)};
        xip[3] = (f32x2){blo(qi.w), bhi(qi.w)};
        xip[4] = (f32x2){blo(ti),   bhi(ti)};
    }
    float ari = ar[i * 8 + h];
    f32x2 accp[5] = {{0.f,0.f},{0.f,0.f},{0.f,0.f},{0.f,0.f},{0.f,0.f}};
    float den = 0.f;

#define C2_CORE(ALJ, XJP) do { \
    f32x2 pdp = xip[0] * (XJP)[0]; \
    pdp += xip[1] * (XJP)[1]; \
    pdp += xip[2] * (XJP)[2]; \
    pdp += xip[3] * (XJP)[3]; \
    pdp += xip[4] * (XJP)[4]; \
    float pd = pdp.x + pdp.y; \
    pd = dpp_xadd1(pd); \
    pd = dpp_xadd2(pd); \
    float a = ((ALJ) + ari) * fast_rcp(1.0f + __expf(-pd)); \
    a = fmaxf(a, 0.2f * a); \
    float e = __expf(a); \
    den += e; \
    f32x2 ev = {e, e}; \
    accp[0] += ev * (XJP)[0]; \
    accp[1] += ev * (XJP)[1]; \
    accp[2] += ev * (XJP)[2]; \
    accp[3] += ev * (XJP)[3]; \
    accp[4] += ev * (XJP)[4]; \
} while (0)

#define C2_UNPACK(DST, U) do { \
    _Pragma("unroll") \
    for (int t = 0; t < 5; ++t) (DST)[t] = (f32x2){blo((U)[t]), bhi((U)[t])}; \
} while (0)

#define C2_FETCH(J, BUF, ALV) do { \
    const uint32_t* _r = xwd + (unsigned)(J) * 20u; \
    uint4 _q = *(const uint4*)(_r + lq4); \
    (BUF)[0] = _q.x; (BUF)[1] = _q.y; (BUF)[2] = _q.z; (BUF)[3] = _q.w; \
    (BUF)[4] = _r[lq1]; \
    (ALV) = al[(J) + h]; \
} while (0)

    if (half == 0) C2_CORE(al[i * 8 + h], xip);   // self loop
    int dg = deg[i];
    int off = btot[i >> 9] + offs[i] - dg;   // offs holds end offsets post-scatter

    int k = half;
    int v0 = (k < dg), v1 = (k + 2 < dg);
    int j0 = fidx(csr8, off + k, v0);
    int j1 = fidx(csr8, off + k + 2, v1);
    uint32_t cA[5], cB[5], dA[5], dB[5];
    float alA, alB, alC, alD;
    C2_FETCH(j0, cA, alA);
    C2_FETCH(j1, cB, alB);
    while (v0) {
        // prefetch pair (k+4, k+6)
        int k4 = k + 4;
        int w0 = (k4 < dg), w1 = (k4 + 2 < dg);
        int m0 = fidx(csr8, off + k4, w0);
        int m1 = fidx(csr8, off + k4 + 2, w1);
        C2_FETCH(m0, dA, alC);
        C2_FETCH(m1, dB, alD);
        // compute current pair
        { f32x2 xj[5]; C2_UNPACK(xj, cA); C2_CORE(alA, xj); }
        if (v1) { f32x2 xj[5]; C2_UNPACK(xj, cB); C2_CORE(alB, xj); }
        if (!w0) break;
        // prefetch pair (k+8, k+10)
        int k8 = k + 8;
        v0 = (k8 < dg); v1 = (k8 + 2 < dg);
        int p0 = fidx(csr8, off + k8, v0);
        int p1 = fidx(csr8, off + k8 + 2, v1);
        C2_FETCH(p0, cA, alA);
        C2_FETCH(p1, cB, alB);
        // compute prefetched pair
        { f32x2 xj[5]; C2_UNPACK(xj, dA); C2_CORE(alC, xj); }
        if (w1) { f32x2 xj[5]; C2_UNPACK(xj, dB); C2_CORE(alD, xj); }
        k = k8;
    }
#undef C2_CORE
#undef C2_UNPACK
#undef C2_FETCH

    float acc[10] = {accp[0].x, accp[0].y, accp[1].x, accp[1].y, accp[2].x,
                     accp[2].y, accp[3].x, accp[3].y, accp[4].x, accp[4].y};
    #pragma unroll
    for (int t = 0; t < 10; ++t) acc[t] += __shfl_xor(acc[t], 32);
    den += __shfl_xor(den, 32);
    float inv = 0.125f * fast_rcp(den + 1e-16f);
    #pragma unroll
    for (int t = 0; t < 10; ++t) acc[t] *= inv;
    #pragma unroll
    for (int o = 4; o <= 16; o <<= 1) {
        #pragma unroll
        for (int t = 0; t < 10; ++t) acc[t] += __shfl_xor(acc[t], o);
    }
    // fused +b2 and log_softmax; lane q holds channels {8q..8q+7, 32+2q, 33+2q}
    #pragma unroll
    for (int t = 0; t < 8; ++t) acc[t] += b2[8 * q + t];
    acc[8] += b2[32 + 2 * q];
    acc[9] += b2[33 + 2 * q];
    float mx = acc[0];
    #pragma unroll
    for (int t = 1; t < 10; ++t) mx = fmaxf(mx, acc[t]);
    mx = fmaxf(mx, __shfl_xor(mx, 1));
    mx = fmaxf(mx, __shfl_xor(mx, 2));
    float s = 0.f;
    #pragma unroll
    for (int t = 0; t < 10; ++t) s += __expf(acc[t] - mx);
    s += __shfl_xor(s, 1);
    s += __shfl_xor(s, 2);
    float lse = mx + __logf(s);
    if (lane < 4) {
        float4* po = (float4*)(out + (long)i * 40 + 8 * q);
        po[0] = make_float4(acc[0] - lse, acc[1] - lse, acc[2] - lse, acc[3] - lse);
        po[1] = make_float4(acc[4] - lse, acc[5] - lse, acc[6] - lse, acc[7] - lse);
        float2* pt = (float2*)(out + (long)i * 40 + 32 + 2 * q);
        *pt = make_float2(acc[8] - lse, acc[9] - lse);
    }
}

extern "C" void kernel_launch(void* const* d_in, const int* in_sizes, int n_in,
                              void* d_out, int out_size, void* d_ws, size_t ws_size,
                              hipStream_t stream) {
    const float* x      = (const float*)d_in[0];
    const int*   ei     = (const int*)d_in[1];
    const float* W1     = (const float*)d_in[2];
    const float* att_l1 = (const float*)d_in[3];
    const float* att_r1 = (const float*)d_in[4];
    const float* b1     = (const float*)d_in[5];
    const float* W2     = (const float*)d_in[6];
    const float* att_l2 = (const float*)d_in[7];
    const float* att_r2 = (const float*)d_in[8];
    const float* b2     = (const float*)d_in[9];
    const int* src = ei;
    const int* dst = ei + N_EDGES;
    float* out = (float*)d_out;

    char* ws = (char*)d_ws;
    float*    xw1    = (float*)(ws + 0);            // 25.6 MB
    float*    hbuf   = (float*)(ws + 25600000);     // 25.6 MB (f32 h)
    uint16_t* xw2b   = (uint16_t*)(ws + 51200000);  // 64 MB (bf16)
    // xw1b aliases the first 12.8 MB of xw2b: dead before gemm2 writes xw2b
    uint16_t* xw1b   = (uint16_t*)(ws + 51200000);  // 12.8 MB (dead after conv1)
    float*    al     = (float*)(ws + 115200000);    // 3.2 MB
    float*    ar     = (float*)(ws + 118400000);    // 3.2 MB
    int*      deg    = (int*)(ws + 121600000);      // 400 KB
    int*      offs   = (int*)(ws + 122000000);      // 400 KB
    int*      btot   = (int*)(ws + 122800000);      // 1 KB
    int*      csr8   = (int*)(ws + 122801024);      // 6.4 MB
    uint16_t* w1hi   = (uint16_t*)(ws + 129201024); // 64 KB
    uint16_t* w1lo   = (uint16_t*)(ws + 129266560); // 64 KB
    uint16_t* w2T    = (uint16_t*)(ws + 129332096); // 40 KB
    float*    wl2    = (float*)(ws + 129373056);    // 2 KB
    float*    wr2    = (float*)(ws + 129375104);    // 2 KB -> ~129.4 MB total

    hipMemsetAsync(deg, 0, (size_t)N_NODES * 4, stream);

    // prep (blocks 0-9) + hist (blocks 10..3134)
    prep_hist_k<<<3135, 512, 0, stream>>>(W1, W2, att_l2, att_r2,
                                          w1hi, w1lo, wl2, wr2, w2T, dst, deg);

    // scans: offs = block-local exclusive prefix; btot = per-block global offsets
    scan_a<<<SCAN_NB, 512, 0, stream>>>(deg, offs, btot);
    scan_b<<<1, 256, 0, stream>>>(btot);

    // gemm1 (blocks 0..781) + scatter (blocks 782..2344)
    // scatter: csr8[btot[d>>9] + atomicAdd(&offs[d],1)] = src*8  (offs -> end)
    gemm1_scatter<<<2345, 512, 0, stream>>>(x, w1hi, w1lo, xw1, xw1b,
                                            src, dst, offs, btot, csr8);

    // conv1 (bf16 gathers; al/ar fused into epilogue)
    conv1_node<<<25000, 256, 0, stream>>>(xw1, xw1b, offs, deg, btot, csr8,
                                          att_l1, att_r1, b1, wl2, wr2,
                                          hbuf, al, ar);

    // conv2 (log_softmax fused into conv2_node)
    gemm2_mfma<<<782, 512, 0, stream>>>(hbuf, w2T, xw2b);
    conv2_node<<<25000, 256, 0, stream>>>(xw2b, offs, deg, btot, csr8, al, ar, b2, out);
}